// Round 4
// baseline (312.529 us; speedup 1.0000x reference)
//
#include <hip/hip_runtime.h>

// Problem constants
#define D      256
#define L_W    20
#define E_CNT  20000
#define VOCAB  50000

// Workspace layout (float offsets)
#define OFF_QEMB  0          // [256]
#define OFF_X     256        // [256]
#define OFF_Y     512        // [256]
#define OFF_WTE1  768        // [256]
#define OFF_SUMW  1024       // scalar
#define OFF_SUML  1025       // scalar
#define OFF_A     1032       // [VOCAB]
#define OFF_B     (OFF_A + VOCAB)       // [VOCAB]
#define OFF_P     (OFF_B + VOCAB)       // [VOCAB]
#define OFF_Q     (OFF_P + VOCAB)       // [VOCAB]
#define OFF_EXPW  (OFF_Q + VOCAB)       // [E_CNT]
#define OFF_EXPL  (OFF_EXPW + E_CNT)    // [VOCAB]
// total = OFF_EXPL + VOCAB = 271032 floats ~= 1.06 MB of ws

__device__ __forceinline__ float wave_reduce(float v) {
#pragma unroll
    for (int o = 32; o > 0; o >>= 1) v += __shfl_xor(v, o, 64);
    return v;
}

// u_j = 1 - 2j/D, s_j = j/D;  pe[l][j] = a_l*u_j + s_j with a_l = 1 - l/L
__device__ __forceinline__ float u_of(int j) { return 1.f - (float)j * (1.f / 128.f); }
__device__ __forceinline__ float s_of(int j) { return (float)j * (1.f / 256.f); }

// K1: q_emb[j] = sum_i q_table[question[i]][j] * pe[i][j]; also zero small accumulators.
__global__ void k1_qemb(const int* __restrict__ question,
                        const float* __restrict__ q_table,
                        float* __restrict__ ws) {
    __shared__ int sQ[L_W];
    int tid = threadIdx.x;
    if (tid < L_W) sQ[tid] = question[tid];
    __syncthreads();
    int j = tid;
    float u = u_of(j), s = s_of(j);
    float acc = 0.f;
#pragma unroll
    for (int i = 0; i < L_W; ++i) {
        float a = 1.f - (float)i * (1.f / (float)L_W);
        acc += q_table[(size_t)sQ[i] * D + j] * (a * u + s);
    }
    ws[OFF_QEMB + j] = acc;
    ws[OFF_X + j] = 0.f;
    ws[OFF_Y + j] = 0.f;
    ws[OFF_WTE1 + j] = 0.f;
    if (tid == 0) { ws[OFF_SUMW] = 0.f; ws[OFF_SUML] = 0.f; }
}

// K2: per vocab row v: A[v] = <q_table[v], u .* q_emb>, B[v] = <q_table[v], s .* q_emb>.
// Also zero P[v], Q[v]. One wave per row, 4 rows per block, exact grid 12500.
__global__ void k2_ab(const float* __restrict__ q_table, float* __restrict__ ws) {
    __shared__ float sQE[D];
    int tid = threadIdx.x;
    sQE[tid] = ws[OFF_QEMB + tid];
    __syncthreads();
    int wv = tid >> 6, lane = tid & 63;
    int v = blockIdx.x * 4 + wv;
    int j0 = lane * 4;
    const float4 q = *reinterpret_cast<const float4*>(&q_table[(size_t)v * D + j0]);
    float qe0 = sQE[j0], qe1 = sQE[j0 + 1], qe2 = sQE[j0 + 2], qe3 = sQE[j0 + 3];
    float accA = q.x * (u_of(j0) * qe0) + q.y * (u_of(j0 + 1) * qe1) +
                 q.z * (u_of(j0 + 2) * qe2) + q.w * (u_of(j0 + 3) * qe3);
    float accB = q.x * (s_of(j0) * qe0) + q.y * (s_of(j0 + 1) * qe1) +
                 q.z * (s_of(j0 + 2) * qe2) + q.w * (s_of(j0 + 3) * qe3);
    accA = wave_reduce(accA);
    accB = wave_reduce(accB);
    if (lane == 0) {
        ws[OFF_A + v] = accA;
        ws[OFF_B + v] = accB;
        ws[OFF_P + v] = 0.f;
        ws[OFF_Q + v] = 0.f;
    }
}

// K3: scores -> exp(score), partial sums -> atomicAdd(sumw).
// score[e] = sum_l (a_l*A[ev] + B[ev]) + <te2[e], q_emb>. One wave per evidence row.
__global__ void k3_scores(const int* __restrict__ evidence,
                          const float* __restrict__ te2,
                          float* __restrict__ ws) {
    __shared__ float sQE[D];
    __shared__ float sPart[4];
    int tid = threadIdx.x;
    sQE[tid] = ws[OFF_QEMB + tid];
    __syncthreads();
    int wv = tid >> 6, lane = tid & 63;
    int gw = blockIdx.x * 4 + wv;
    int stride = gridDim.x * 4;
    int j0 = lane * 4;
    const float4 qe = *reinterpret_cast<const float4*>(&sQE[j0]);
    float wsum = 0.f;
    for (int e = gw; e < E_CNT; e += stride) {
        const float4 t = *reinterpret_cast<const float4*>(&te2[(size_t)e * D + j0]);
        float p = t.x * qe.x + t.y * qe.y + t.z * qe.z + t.w * qe.w;
        if (lane < L_W) {
            int idx = evidence[e * L_W + lane];
            float a = 1.f - (float)lane * (1.f / (float)L_W);
            p += a * ws[OFF_A + idx] + ws[OFF_B + idx];
        }
        float s_e = wave_reduce(p);
        float ex = expf(s_e);
        if (lane == 0) ws[OFF_EXPW + e] = ex;
        wsum += ex;  // uniform across lanes after reduce
    }
    if (lane == 0) sPart[wv] = wsum;
    __syncthreads();
    if (tid == 0) atomicAdd(&ws[OFF_SUMW], sPart[0] + sPart[1] + sPart[2] + sPart[3]);
}

// K5: normalized weights w_e = expw[e]/sumw.
// Scatter: P[v] += w_e*a_l, Q[v] += w_e  for each (e,l).
// Also wte1[j] += sum_e w_e * te1[e][j] (block LDS combine + 1 atomic per j per block).
__global__ void k5_scatter(const int* __restrict__ evidence,
                           const float* __restrict__ te1,
                           float* __restrict__ ws) {
    __shared__ float sWT[D];
    int tid = threadIdx.x;
    sWT[tid] = 0.f;
    __syncthreads();
    float inv = 1.f / ws[OFF_SUMW];
    int wv = tid >> 6, lane = tid & 63;
    int gw = blockIdx.x * 4 + wv;
    int stride = gridDim.x * 4;
    int j0 = lane * 4;
    float a0 = 0.f, a1 = 0.f, a2 = 0.f, a3 = 0.f;
    for (int e = gw; e < E_CNT; e += stride) {
        float w = ws[OFF_EXPW + e] * inv;
        const float4 t = *reinterpret_cast<const float4*>(&te1[(size_t)e * D + j0]);
        a0 += w * t.x; a1 += w * t.y; a2 += w * t.z; a3 += w * t.w;
        if (lane < L_W) {
            int idx = evidence[e * L_W + lane];
            float a = 1.f - (float)lane * (1.f / (float)L_W);
            atomicAdd(&ws[OFF_P + idx], w * a);
            atomicAdd(&ws[OFF_Q + idx], w);
        }
    }
    atomicAdd(&sWT[j0 + 0], a0);
    atomicAdd(&sWT[j0 + 1], a1);
    atomicAdd(&sWT[j0 + 2], a2);
    atomicAdd(&sWT[j0 + 3], a3);
    __syncthreads();
    atomicAdd(&ws[OFF_WTE1 + tid], sWT[tid]);
}

// K6: X[j] = sum_v P[v]*e_table[v][j], Y[j] = sum_v Q[v]*e_table[v][j].
__global__ void k6_xy(const float* __restrict__ e_table, float* __restrict__ ws) {
    __shared__ float sX[D], sY[D];
    int tid = threadIdx.x;
    sX[tid] = 0.f;
    sY[tid] = 0.f;
    __syncthreads();
    int wv = tid >> 6, lane = tid & 63;
    int gw = blockIdx.x * 4 + wv;
    int stride = gridDim.x * 4;
    int j0 = lane * 4;
    float x0 = 0.f, x1 = 0.f, x2 = 0.f, x3 = 0.f;
    float y0 = 0.f, y1 = 0.f, y2 = 0.f, y3 = 0.f;
    for (int v = gw; v < VOCAB; v += stride) {
        float P = ws[OFF_P + v];
        float Q = ws[OFF_Q + v];
        const float4 t = *reinterpret_cast<const float4*>(&e_table[(size_t)v * D + j0]);
        x0 += P * t.x; x1 += P * t.y; x2 += P * t.z; x3 += P * t.w;
        y0 += Q * t.x; y1 += Q * t.y; y2 += Q * t.z; y3 += Q * t.w;
    }
    atomicAdd(&sX[j0 + 0], x0); atomicAdd(&sX[j0 + 1], x1);
    atomicAdd(&sX[j0 + 2], x2); atomicAdd(&sX[j0 + 3], x3);
    atomicAdd(&sY[j0 + 0], y0); atomicAdd(&sY[j0 + 1], y1);
    atomicAdd(&sY[j0 + 2], y2); atomicAdd(&sY[j0 + 3], y3);
    __syncthreads();
    atomicAdd(&ws[OFF_X + tid], sX[tid]);
    atomicAdd(&ws[OFF_Y + tid], sY[tid]);
}

// K8: features[j] = u_j*X[j] + s_j*Y[j] + wte1[j] + q_emb[j];
// expL[v] = exp(<W[v], features> + b[v]); partial sums -> atomicAdd(sumL).
__global__ void k8_logits(const float* __restrict__ Wm, const float* __restrict__ bv,
                          float* __restrict__ ws) {
    __shared__ float sF[D];
    __shared__ float sPart[4];
    int tid = threadIdx.x;
    {
        int j = tid;
        sF[j] = u_of(j) * ws[OFF_X + j] + s_of(j) * ws[OFF_Y + j] +
                ws[OFF_WTE1 + j] + ws[OFF_QEMB + j];
    }
    __syncthreads();
    int wv = tid >> 6, lane = tid & 63;
    int gw = blockIdx.x * 4 + wv;
    int stride = gridDim.x * 4;
    int j0 = lane * 4;
    const float4 f = *reinterpret_cast<const float4*>(&sF[j0]);
    float lsum = 0.f;
    for (int v = gw; v < VOCAB; v += stride) {
        const float4 w4 = *reinterpret_cast<const float4*>(&Wm[(size_t)v * D + j0]);
        float p = w4.x * f.x + w4.y * f.y + w4.z * f.z + w4.w * f.w;
        float logit = wave_reduce(p) + bv[v];
        float ex = expf(logit);
        if (lane == 0) ws[OFF_EXPL + v] = ex;
        lsum += ex;  // uniform across lanes
    }
    if (lane == 0) sPart[wv] = lsum;
    __syncthreads();
    if (tid == 0) atomicAdd(&ws[OFF_SUML], sPart[0] + sPart[1] + sPart[2] + sPart[3]);
}

// K10: out[v] = expL[v] / sumL
__global__ void k10_norm(float* __restrict__ out, const float* __restrict__ ws) {
    int i = blockIdx.x * 256 + threadIdx.x;
    if (i < VOCAB) out[i] = ws[OFF_EXPL + i] * (1.f / ws[OFF_SUML]);
}

extern "C" void kernel_launch(void* const* d_in, const int* in_sizes, int n_in,
                              void* d_out, int out_size, void* d_ws, size_t ws_size,
                              hipStream_t stream) {
    const int*   evidence = (const int*)d_in[0];
    const int*   question = (const int*)d_in[1];
    const float* q_table  = (const float*)d_in[2];
    const float* e_table  = (const float*)d_in[3];
    const float* te1      = (const float*)d_in[4];
    const float* te2      = (const float*)d_in[5];
    const float* Wm       = (const float*)d_in[6];
    const float* bv       = (const float*)d_in[7];
    float* out = (float*)d_out;
    float* ws  = (float*)d_ws;

    k1_qemb<<<1, 256, 0, stream>>>(question, q_table, ws);
    k2_ab<<<VOCAB / 4, 256, 0, stream>>>(q_table, ws);
    k3_scores<<<512, 256, 0, stream>>>(evidence, te2, ws);
    k5_scatter<<<512, 256, 0, stream>>>(evidence, te1, ws);
    k6_xy<<<1024, 256, 0, stream>>>(e_table, ws);
    k8_logits<<<1024, 256, 0, stream>>>(Wm, bv, ws);
    k10_norm<<<(VOCAB + 255) / 256, 256, 0, stream>>>(out, ws);
}

// Round 7
// 295.954 us; speedup vs baseline: 1.0560x; 1.0560x over previous
//
#include <hip/hip_runtime.h>

// Problem constants
#define D      256
#define L_W    20
#define E_CNT  20000
#define VOCAB  50000

// Scatter privatization geometry
#define CHUNK   1024
#define NCHUNK  49                   // 49*1024 = 50176 >= VOCAB
#define NSLICE  8
#define RPS     (E_CNT / NSLICE)     // 2500 rows per slice
#define PSTRIDE (NCHUNK * CHUNK)     // 50176
#define WTB     256                  // blocks for k5c wte1 partials

// Workspace layout (float offsets)
#define OFF_QEMB  0          // [256]
#define OFF_X     256        // [256]
#define OFF_Y     512        // [256]
#define OFF_WTE1  768        // [256]
#define OFF_SUMW  1024       // scalar
#define OFF_SUML  1025       // scalar
#define OFF_A     1032       // [VOCAB]
#define OFF_B     (OFF_A + VOCAB)        // [VOCAB]
#define OFF_P     (OFF_B + VOCAB)        // [VOCAB]
#define OFF_Q     (OFF_P + VOCAB)        // [VOCAB]
#define OFF_EXPW  (OFF_Q + VOCAB)        // [E_CNT]
#define OFF_EXPL  (OFF_EXPW + E_CNT)     // [VOCAB]
#define OFF_PPART (OFF_EXPL + VOCAB)             // [NSLICE][PSTRIDE]
#define OFF_QPART (OFF_PPART + NSLICE * PSTRIDE) // [NSLICE][PSTRIDE]
#define OFF_WTP   (OFF_QPART + NSLICE * PSTRIDE) // [WTB][D]
#define WS_FLOATS (OFF_WTP + WTB * D)            // 1,139,384 floats ~= 4.56 MB

__device__ __forceinline__ float wave_reduce(float v) {
#pragma unroll
    for (int o = 32; o > 0; o >>= 1) v += __shfl_xor(v, o, 64);
    return v;
}

// u_j = 1 - 2j/D, s_j = j/D;  pe[l][j] = a_l*u_j + s_j with a_l = 1 - l/L
__device__ __forceinline__ float u_of(int j) { return 1.f - (float)j * (1.f / 128.f); }
__device__ __forceinline__ float s_of(int j) { return (float)j * (1.f / 256.f); }

// K1: q_emb + zero small accumulators.
__global__ void k1_qemb(const int* __restrict__ question,
                        const float* __restrict__ q_table,
                        float* __restrict__ ws) {
    __shared__ int sQ[L_W];
    int tid = threadIdx.x;
    if (tid < L_W) sQ[tid] = question[tid];
    __syncthreads();
    int j = tid;
    float u = u_of(j), s = s_of(j);
    float acc = 0.f;
#pragma unroll
    for (int i = 0; i < L_W; ++i) {
        float a = 1.f - (float)i * (1.f / (float)L_W);
        acc += q_table[(size_t)sQ[i] * D + j] * (a * u + s);
    }
    ws[OFF_QEMB + j] = acc;
    ws[OFF_X + j] = 0.f;
    ws[OFF_Y + j] = 0.f;
    ws[OFF_WTE1 + j] = 0.f;
    if (tid == 0) { ws[OFF_SUMW] = 0.f; ws[OFF_SUML] = 0.f; }
}

// K2: A[v] = <q_table[v], u.*q_emb>, B[v] = <q_table[v], s.*q_emb>; zero P/Q (fallback path needs it).
__global__ void k2_ab(const float* __restrict__ q_table, float* __restrict__ ws) {
    __shared__ float sQE[D];
    int tid = threadIdx.x;
    sQE[tid] = ws[OFF_QEMB + tid];
    __syncthreads();
    int wv = tid >> 6, lane = tid & 63;
    int v = blockIdx.x * 4 + wv;
    int j0 = lane * 4;
    const float4 q = *reinterpret_cast<const float4*>(&q_table[(size_t)v * D + j0]);
    float qe0 = sQE[j0], qe1 = sQE[j0 + 1], qe2 = sQE[j0 + 2], qe3 = sQE[j0 + 3];
    float accA = q.x * (u_of(j0) * qe0) + q.y * (u_of(j0 + 1) * qe1) +
                 q.z * (u_of(j0 + 2) * qe2) + q.w * (u_of(j0 + 3) * qe3);
    float accB = q.x * (s_of(j0) * qe0) + q.y * (s_of(j0 + 1) * qe1) +
                 q.z * (s_of(j0 + 2) * qe2) + q.w * (s_of(j0 + 3) * qe3);
    accA = wave_reduce(accA);
    accB = wave_reduce(accB);
    if (lane == 0) {
        ws[OFF_A + v] = accA;
        ws[OFF_B + v] = accB;
        ws[OFF_P + v] = 0.f;
        ws[OFF_Q + v] = 0.f;
    }
}

// K3: exp(score) per evidence; gather of A/B spread over 40 lanes (1 load each).
__global__ void k3_scores(const int* __restrict__ evidence,
                          const float* __restrict__ te2,
                          float* __restrict__ ws) {
    __shared__ float sQE[D];
    __shared__ float sPart[4];
    int tid = threadIdx.x;
    sQE[tid] = ws[OFF_QEMB + tid];
    __syncthreads();
    int wv = tid >> 6, lane = tid & 63;
    int gw = blockIdx.x * 4 + wv;
    int stride = gridDim.x * 4;
    int j0 = lane * 4;
    const float4 qe = *reinterpret_cast<const float4*>(&sQE[j0]);
    float wsum = 0.f;
    for (int e = gw; e < E_CNT; e += stride) {
        const float4 t = *reinterpret_cast<const float4*>(&te2[(size_t)e * D + j0]);
        float p = t.x * qe.x + t.y * qe.y + t.z * qe.z + t.w * qe.w;
        if (lane < 2 * L_W) {
            int l = (lane < L_W) ? lane : (lane - L_W);
            int idx = evidence[e * L_W + l];
            if (lane < L_W) {
                float a = 1.f - (float)l * (1.f / (float)L_W);
                p += a * ws[OFF_A + idx];
            } else {
                p += ws[OFF_B + idx];
            }
        }
        float s_e = wave_reduce(p);
        float ex = expf(s_e);
        if (lane == 0) ws[OFF_EXPW + e] = ex;
        wsum += ex;
    }
    if (lane == 0) sPart[wv] = wsum;
    __syncthreads();
    if (tid == 0) atomicAdd(&ws[OFF_SUMW], sPart[0] + sPart[1] + sPart[2] + sPart[3]);
}

// K5v2: atomic-free P/Q scatter. Block = (chunk, slice): LDS histogram of its
// 1024-vocab chunk over its 2500-row evidence slice; non-atomic partial write-out.
__global__ void k5_scatter2(const int* __restrict__ evidence, float* __restrict__ ws) {
    __shared__ float sP[CHUNK], sQ[CHUNK];
    int tid = threadIdx.x;
    int chunk = blockIdx.x % NCHUNK;
    int slice = blockIdx.x / NCHUNK;
    for (int i = tid; i < CHUNK; i += 256) { sP[i] = 0.f; sQ[i] = 0.f; }
    __syncthreads();
    int lo = chunk * CHUNK;
    float inv = 1.f / ws[OFF_SUMW];
    int r0 = slice * RPS;
    for (int r = tid; r < RPS; r += 256) {
        int e = r0 + r;
        float w = ws[OFF_EXPW + e] * inv;
        const int4* rp = reinterpret_cast<const int4*>(evidence + (size_t)e * L_W);
        int4 v0 = rp[0], v1 = rp[1], v2 = rp[2], v3 = rp[3], v4 = rp[4];
        int idxs[L_W] = {v0.x, v0.y, v0.z, v0.w, v1.x, v1.y, v1.z, v1.w,
                         v2.x, v2.y, v2.z, v2.w, v3.x, v3.y, v3.z, v3.w,
                         v4.x, v4.y, v4.z, v4.w};
#pragma unroll
        for (int l = 0; l < L_W; ++l) {
            int d = idxs[l] - lo;
            if ((unsigned)d < (unsigned)CHUNK) {
                float a = 1.f - (float)l * (1.f / (float)L_W);
                atomicAdd(&sP[d], w * a);
                atomicAdd(&sQ[d], w);
            }
        }
    }
    __syncthreads();
    float* pp = &ws[OFF_PPART + (size_t)slice * PSTRIDE + (size_t)chunk * CHUNK];
    float* qp = &ws[OFF_QPART + (size_t)slice * PSTRIDE + (size_t)chunk * CHUNK];
    for (int i = tid; i < CHUNK; i += 256) { pp[i] = sP[i]; qp[i] = sQ[i]; }
}

// K5c: per-block partials of wte1[j] = sum_e w_e * te1[e][j]  (no global atomics).
__global__ void k5c_wte1(const float* __restrict__ te1, float* __restrict__ ws) {
    __shared__ float sWT[D];
    int tid = threadIdx.x;
    sWT[tid] = 0.f;
    __syncthreads();
    float inv = 1.f / ws[OFF_SUMW];
    int wv = tid >> 6, lane = tid & 63;
    int gw = blockIdx.x * 4 + wv;
    int stride = gridDim.x * 4;
    int j0 = lane * 4;
    float a0 = 0.f, a1 = 0.f, a2 = 0.f, a3 = 0.f;
    for (int e = gw; e < E_CNT; e += stride) {
        float w = ws[OFF_EXPW + e] * inv;
        const float4 t = *reinterpret_cast<const float4*>(&te1[(size_t)e * D + j0]);
        a0 += w * t.x; a1 += w * t.y; a2 += w * t.z; a3 += w * t.w;
    }
    atomicAdd(&sWT[j0 + 0], a0);
    atomicAdd(&sWT[j0 + 1], a1);
    atomicAdd(&sWT[j0 + 2], a2);
    atomicAdd(&sWT[j0 + 3], a3);
    __syncthreads();
    ws[OFF_WTP + blockIdx.x * D + tid] = sWT[tid];
}

// K5b: reduce partials: P/Q over NSLICE, WTE1 over WTB (block 0 only).
__global__ void k5b_reduce(float* __restrict__ ws) {
    int tid = threadIdx.x;
    int v = blockIdx.x * 256 + tid;
    if (v < VOCAB) {
        float p = 0.f, q = 0.f;
#pragma unroll
        for (int s = 0; s < NSLICE; ++s) {
            p += ws[OFF_PPART + s * PSTRIDE + v];
            q += ws[OFF_QPART + s * PSTRIDE + v];
        }
        ws[OFF_P + v] = p;
        ws[OFF_Q + v] = q;
    }
    if (blockIdx.x == 0) {
        float acc = 0.f;
        for (int b = 0; b < WTB; ++b) acc += ws[OFF_WTP + b * D + tid];
        ws[OFF_WTE1 + tid] = acc;
    }
}

// K5 (fallback, used only if ws_size too small): original atomic scatter + wte1.
__global__ void k5_scatter(const int* __restrict__ evidence,
                           const float* __restrict__ te1,
                           float* __restrict__ ws) {
    __shared__ float sWT[D];
    int tid = threadIdx.x;
    sWT[tid] = 0.f;
    __syncthreads();
    float inv = 1.f / ws[OFF_SUMW];
    int wv = tid >> 6, lane = tid & 63;
    int gw = blockIdx.x * 4 + wv;
    int stride = gridDim.x * 4;
    int j0 = lane * 4;
    float a0 = 0.f, a1 = 0.f, a2 = 0.f, a3 = 0.f;
    for (int e = gw; e < E_CNT; e += stride) {
        float w = ws[OFF_EXPW + e] * inv;
        const float4 t = *reinterpret_cast<const float4*>(&te1[(size_t)e * D + j0]);
        a0 += w * t.x; a1 += w * t.y; a2 += w * t.z; a3 += w * t.w;
        if (lane < L_W) {
            int idx = evidence[e * L_W + lane];
            float a = 1.f - (float)lane * (1.f / (float)L_W);
            atomicAdd(&ws[OFF_P + idx], w * a);
            atomicAdd(&ws[OFF_Q + idx], w);
        }
    }
    atomicAdd(&sWT[j0 + 0], a0);
    atomicAdd(&sWT[j0 + 1], a1);
    atomicAdd(&sWT[j0 + 2], a2);
    atomicAdd(&sWT[j0 + 3], a3);
    __syncthreads();
    atomicAdd(&ws[OFF_WTE1 + tid], sWT[tid]);
}

// K6: X[j] = sum_v P[v]*e_table[v][j], Y[j] = sum_v Q[v]*e_table[v][j].
__global__ void k6_xy(const float* __restrict__ e_table, float* __restrict__ ws) {
    __shared__ float sX[D], sY[D];
    int tid = threadIdx.x;
    sX[tid] = 0.f;
    sY[tid] = 0.f;
    __syncthreads();
    int wv = tid >> 6, lane = tid & 63;
    int gw = blockIdx.x * 4 + wv;
    int stride = gridDim.x * 4;
    int j0 = lane * 4;
    float x0 = 0.f, x1 = 0.f, x2 = 0.f, x3 = 0.f;
    float y0 = 0.f, y1 = 0.f, y2 = 0.f, y3 = 0.f;
    for (int v = gw; v < VOCAB; v += stride) {
        float P = ws[OFF_P + v];
        float Q = ws[OFF_Q + v];
        const float4 t = *reinterpret_cast<const float4*>(&e_table[(size_t)v * D + j0]);
        x0 += P * t.x; x1 += P * t.y; x2 += P * t.z; x3 += P * t.w;
        y0 += Q * t.x; y1 += Q * t.y; y2 += Q * t.z; y3 += Q * t.w;
    }
    atomicAdd(&sX[j0 + 0], x0); atomicAdd(&sX[j0 + 1], x1);
    atomicAdd(&sX[j0 + 2], x2); atomicAdd(&sX[j0 + 3], x3);
    atomicAdd(&sY[j0 + 0], y0); atomicAdd(&sY[j0 + 1], y1);
    atomicAdd(&sY[j0 + 2], y2); atomicAdd(&sY[j0 + 3], y3);
    __syncthreads();
    atomicAdd(&ws[OFF_X + tid], sX[tid]);
    atomicAdd(&ws[OFF_Y + tid], sY[tid]);
}

// K8: features + logits softmax-numerator.
__global__ void k8_logits(const float* __restrict__ Wm, const float* __restrict__ bv,
                          float* __restrict__ ws) {
    __shared__ float sF[D];
    __shared__ float sPart[4];
    int tid = threadIdx.x;
    {
        int j = tid;
        sF[j] = u_of(j) * ws[OFF_X + j] + s_of(j) * ws[OFF_Y + j] +
                ws[OFF_WTE1 + j] + ws[OFF_QEMB + j];
    }
    __syncthreads();
    int wv = tid >> 6, lane = tid & 63;
    int gw = blockIdx.x * 4 + wv;
    int stride = gridDim.x * 4;
    int j0 = lane * 4;
    const float4 f = *reinterpret_cast<const float4*>(&sF[j0]);
    float lsum = 0.f;
    for (int v = gw; v < VOCAB; v += stride) {
        const float4 w4 = *reinterpret_cast<const float4*>(&Wm[(size_t)v * D + j0]);
        float p = w4.x * f.x + w4.y * f.y + w4.z * f.z + w4.w * f.w;
        float logit = wave_reduce(p) + bv[v];
        float ex = expf(logit);
        if (lane == 0) ws[OFF_EXPL + v] = ex;
        lsum += ex;
    }
    if (lane == 0) sPart[wv] = lsum;
    __syncthreads();
    if (tid == 0) atomicAdd(&ws[OFF_SUML], sPart[0] + sPart[1] + sPart[2] + sPart[3]);
}

// K10: out[v] = expL[v] / sumL
__global__ void k10_norm(float* __restrict__ out, const float* __restrict__ ws) {
    int i = blockIdx.x * 256 + threadIdx.x;
    if (i < VOCAB) out[i] = ws[OFF_EXPL + i] * (1.f / ws[OFF_SUML]);
}

extern "C" void kernel_launch(void* const* d_in, const int* in_sizes, int n_in,
                              void* d_out, int out_size, void* d_ws, size_t ws_size,
                              hipStream_t stream) {
    const int*   evidence = (const int*)d_in[0];
    const int*   question = (const int*)d_in[1];
    const float* q_table  = (const float*)d_in[2];
    const float* e_table  = (const float*)d_in[3];
    const float* te1      = (const float*)d_in[4];
    const float* te2      = (const float*)d_in[5];
    const float* Wm       = (const float*)d_in[6];
    const float* bv       = (const float*)d_in[7];
    float* out = (float*)d_out;
    float* ws  = (float*)d_ws;

    const bool big = ws_size >= (size_t)WS_FLOATS * sizeof(float);

    k1_qemb<<<1, 256, 0, stream>>>(question, q_table, ws);
    k2_ab<<<VOCAB / 4, 256, 0, stream>>>(q_table, ws);
    k3_scores<<<512, 256, 0, stream>>>(evidence, te2, ws);
    if (big) {
        k5_scatter2<<<NCHUNK * NSLICE, 256, 0, stream>>>(evidence, ws);
        k5c_wte1<<<WTB, 256, 0, stream>>>(te1, ws);
        k5b_reduce<<<(VOCAB + 255) / 256, 256, 0, stream>>>(ws);
    } else {
        k5_scatter<<<512, 256, 0, stream>>>(evidence, te1, ws);
    }
    k6_xy<<<1024, 256, 0, stream>>>(e_table, ws);
    k8_logits<<<1024, 256, 0, stream>>>(Wm, bv, ws);
    k10_norm<<<(VOCAB + 255) / 256, 256, 0, stream>>>(out, ws);
}

// Round 8
// 256.570 us; speedup vs baseline: 1.2181x; 1.1535x over previous
//
#include <hip/hip_runtime.h>

// Problem constants
#define D      256
#define L_W    20
#define E_CNT  20000
#define VOCAB  50000
#define TOTROW (VOCAB + E_CNT)   // k6 streams e_table rows then te1 rows

// Scatter privatization geometry
#define CHUNK   1024
#define NCHUNK  49                   // 49*1024 = 50176 >= VOCAB
#define NSLICE  4
#define RPS     (E_CNT / NSLICE)     // 5000 rows per slice
#define PSTRIDE (NCHUNK * CHUNK)     // 50176

// k6 geometry
#define K6_BLOCKS 512
#define K6_STRIDE 768                // X(256) | Y(256) | T(256) per block

// Workspace layout (float offsets) — all atomic-free partials
#define OFF_QEMB  0                              // [256]
#define OFF_X     256                            // [256]
#define OFF_Y     512                            // [256]
#define OFF_WTE1  768                            // [256]
#define OFF_SWP   1024                           // [512]  k3 per-block exp-sum partials
#define OFF_LP    1536                           // [1024] k8 per-block expL-sum partials
#define OFF_A     2560                           // [VOCAB]
#define OFF_B     (OFF_A + VOCAB)                // [VOCAB]
#define OFF_P     (OFF_B + VOCAB)                // [VOCAB]
#define OFF_Q     (OFF_P + VOCAB)                // [VOCAB]
#define OFF_EXPW  (OFF_Q + VOCAB)                // [E_CNT]
#define OFF_EXPL  (OFF_EXPW + E_CNT)             // [VOCAB]
#define OFF_PPART (OFF_EXPL + VOCAB)             // [NSLICE][PSTRIDE]
#define OFF_QPART (OFF_PPART + NSLICE * PSTRIDE) // [NSLICE][PSTRIDE]
#define OFF_XYP   (OFF_QPART + NSLICE * PSTRIDE) // [K6_BLOCKS][768]
#define WS_FLOATS (OFF_XYP + K6_BLOCKS * K6_STRIDE)  // 1,067,184 floats ~= 4.27 MB

__device__ __forceinline__ float wave_reduce(float v) {
#pragma unroll
    for (int o = 32; o > 0; o >>= 1) v += __shfl_xor(v, o, 64);
    return v;
}

// u_j = 1 - 2j/D, s_j = j/D;  pe[l][j] = a_l*u_j + s_j with a_l = 1 - l/L
__device__ __forceinline__ float u_of(int j) { return 1.f - (float)j * (1.f / 128.f); }
__device__ __forceinline__ float s_of(int j) { return (float)j * (1.f / 256.f); }

// K1: q_emb[j] only.
__global__ void k1_qemb(const int* __restrict__ question,
                        const float* __restrict__ q_table,
                        float* __restrict__ ws) {
    __shared__ int sQ[L_W];
    int tid = threadIdx.x;
    if (tid < L_W) sQ[tid] = question[tid];
    __syncthreads();
    int j = tid;
    float u = u_of(j), s = s_of(j);
    float acc = 0.f;
#pragma unroll
    for (int i = 0; i < L_W; ++i) {
        float a = 1.f - (float)i * (1.f / (float)L_W);
        acc += q_table[(size_t)sQ[i] * D + j] * (a * u + s);
    }
    ws[OFF_QEMB + j] = acc;
}

// K2: A[v] = <q_table[v], u.*q_emb>, B[v] = <q_table[v], s.*q_emb>; zero P/Q for fallback.
__global__ void k2_ab(const float* __restrict__ q_table, float* __restrict__ ws) {
    __shared__ float sQE[D];
    int tid = threadIdx.x;
    sQE[tid] = ws[OFF_QEMB + tid];
    __syncthreads();
    int wv = tid >> 6, lane = tid & 63;
    int v = blockIdx.x * 4 + wv;
    int j0 = lane * 4;
    const float4 q = *reinterpret_cast<const float4*>(&q_table[(size_t)v * D + j0]);
    float qe0 = sQE[j0], qe1 = sQE[j0 + 1], qe2 = sQE[j0 + 2], qe3 = sQE[j0 + 3];
    float accA = q.x * (u_of(j0) * qe0) + q.y * (u_of(j0 + 1) * qe1) +
                 q.z * (u_of(j0 + 2) * qe2) + q.w * (u_of(j0 + 3) * qe3);
    float accB = q.x * (s_of(j0) * qe0) + q.y * (s_of(j0 + 1) * qe1) +
                 q.z * (s_of(j0 + 2) * qe2) + q.w * (s_of(j0 + 3) * qe3);
    accA = wave_reduce(accA);
    accB = wave_reduce(accB);
    if (lane == 0) {
        ws[OFF_A + v] = accA;
        ws[OFF_B + v] = accB;
        ws[OFF_P + v] = 0.f;
        ws[OFF_Q + v] = 0.f;
    }
}

// K3: exp(score) per evidence; per-block partial sums -> SWP[blk] (NO global atomics).
__global__ void k3_scores(const int* __restrict__ evidence,
                          const float* __restrict__ te2,
                          float* __restrict__ ws) {
    __shared__ float sQE[D];
    __shared__ float sPart[4];
    int tid = threadIdx.x;
    sQE[tid] = ws[OFF_QEMB + tid];
    __syncthreads();
    int wv = tid >> 6, lane = tid & 63;
    int gw = blockIdx.x * 4 + wv;
    int stride = gridDim.x * 4;
    int j0 = lane * 4;
    const float4 qe = *reinterpret_cast<const float4*>(&sQE[j0]);
    float wsum = 0.f;
    for (int e = gw; e < E_CNT; e += stride) {
        const float4 t = *reinterpret_cast<const float4*>(&te2[(size_t)e * D + j0]);
        float p = t.x * qe.x + t.y * qe.y + t.z * qe.z + t.w * qe.w;
        if (lane < 2 * L_W) {
            int l = (lane < L_W) ? lane : (lane - L_W);
            int idx = evidence[e * L_W + l];
            if (lane < L_W) {
                float a = 1.f - (float)l * (1.f / (float)L_W);
                p += a * ws[OFF_A + idx];
            } else {
                p += ws[OFF_B + idx];
            }
        }
        float s_e = wave_reduce(p);
        float ex = expf(s_e);
        if (lane == 0) ws[OFF_EXPW + e] = ex;
        wsum += ex;
    }
    if (lane == 0) sPart[wv] = wsum;
    __syncthreads();
    if (tid == 0) ws[OFF_SWP + blockIdx.x] = sPart[0] + sPart[1] + sPart[2] + sPart[3];
}

// K5v2: atomic-free P/Q scatter with UNNORMALIZED weights ex_e.
__global__ void k5_scatter2(const int* __restrict__ evidence, float* __restrict__ ws) {
    __shared__ float sP[CHUNK], sQ[CHUNK];
    int tid = threadIdx.x;
    int chunk = blockIdx.x % NCHUNK;
    int slice = blockIdx.x / NCHUNK;
    for (int i = tid; i < CHUNK; i += 256) { sP[i] = 0.f; sQ[i] = 0.f; }
    __syncthreads();
    int lo = chunk * CHUNK;
    int r0 = slice * RPS;
    for (int r = tid; r < RPS; r += 256) {
        int e = r0 + r;
        float w = ws[OFF_EXPW + e];
        const int4* rp = reinterpret_cast<const int4*>(evidence + (size_t)e * L_W);
        int4 v0 = rp[0], v1 = rp[1], v2 = rp[2], v3 = rp[3], v4 = rp[4];
        int idxs[L_W] = {v0.x, v0.y, v0.z, v0.w, v1.x, v1.y, v1.z, v1.w,
                         v2.x, v2.y, v2.z, v2.w, v3.x, v3.y, v3.z, v3.w,
                         v4.x, v4.y, v4.z, v4.w};
#pragma unroll
        for (int l = 0; l < L_W; ++l) {
            int d = idxs[l] - lo;
            if ((unsigned)d < (unsigned)CHUNK) {
                float a = 1.f - (float)l * (1.f / (float)L_W);
                atomicAdd(&sP[d], w * a);   // LDS atomics only
                atomicAdd(&sQ[d], w);
            }
        }
    }
    __syncthreads();
    float* pp = &ws[OFF_PPART + (size_t)slice * PSTRIDE + (size_t)chunk * CHUNK];
    float* qp = &ws[OFF_QPART + (size_t)slice * PSTRIDE + (size_t)chunk * CHUNK];
    for (int i = tid; i < CHUNK; i += 256) { pp[i] = sP[i]; qp[i] = sQ[i]; }
}

// K5b: reduce P/Q partials over NSLICE (non-atomic overwrite).
__global__ void k5b_reduce(float* __restrict__ ws) {
    int v = blockIdx.x * 256 + threadIdx.x;
    if (v < VOCAB) {
        float p = 0.f, q = 0.f;
#pragma unroll
        for (int s = 0; s < NSLICE; ++s) {
            p += ws[OFF_PPART + s * PSTRIDE + v];
            q += ws[OFF_QPART + s * PSTRIDE + v];
        }
        ws[OFF_P + v] = p;
        ws[OFF_Q + v] = q;
    }
}

// K5 fallback (small ws): atomic P/Q scatter with raw ex.
__global__ void k5_scatter(const int* __restrict__ evidence, float* __restrict__ ws) {
    int tid = threadIdx.x;
    int wv = tid >> 6, lane = tid & 63;
    int gw = blockIdx.x * 4 + wv;
    int stride = gridDim.x * 4;
    for (int e = gw; e < E_CNT; e += stride) {
        float w = ws[OFF_EXPW + e];
        if (lane < L_W) {
            int idx = evidence[e * L_W + lane];
            float a = 1.f - (float)lane * (1.f / (float)L_W);
            atomicAdd(&ws[OFF_P + idx], w * a);
            atomicAdd(&ws[OFF_Q + idx], w);
        }
    }
}

// K6: one fused stream over e_table (50000 rows, P/Q weights) + te1 (20000 rows, EXPW weight).
// 4 rows per wave per iteration; block LDS combine; NON-ATOMIC per-block partial [768].
__global__ void k6_xyt(const float* __restrict__ e_table,
                       const float* __restrict__ te1,
                       float* __restrict__ ws) {
    __shared__ float sAcc[K6_STRIDE];
    int tid = threadIdx.x;
    for (int i = tid; i < K6_STRIDE; i += 256) sAcc[i] = 0.f;
    __syncthreads();
    int wv = tid >> 6, lane = tid & 63;
    int gw = blockIdx.x * 4 + wv;          // 2048 waves
    int nw = gridDim.x * 4;
    int j0 = lane * 4;
    float x0 = 0.f, x1 = 0.f, x2 = 0.f, x3 = 0.f;
    float y0 = 0.f, y1 = 0.f, y2 = 0.f, y3 = 0.f;
    float t0 = 0.f, t1 = 0.f, t2 = 0.f, t3 = 0.f;
    for (int v0 = gw * 4; v0 < TOTROW; v0 += nw * 4) {
        if (v0 < VOCAB) {
            const float4 P4 = *reinterpret_cast<const float4*>(&ws[OFF_P + v0]);
            const float4 Q4 = *reinterpret_cast<const float4*>(&ws[OFF_Q + v0]);
            const float4 r0 = *reinterpret_cast<const float4*>(&e_table[(size_t)(v0 + 0) * D + j0]);
            const float4 r1 = *reinterpret_cast<const float4*>(&e_table[(size_t)(v0 + 1) * D + j0]);
            const float4 r2 = *reinterpret_cast<const float4*>(&e_table[(size_t)(v0 + 2) * D + j0]);
            const float4 r3 = *reinterpret_cast<const float4*>(&e_table[(size_t)(v0 + 3) * D + j0]);
            x0 += P4.x * r0.x + P4.y * r1.x + P4.z * r2.x + P4.w * r3.x;
            x1 += P4.x * r0.y + P4.y * r1.y + P4.z * r2.y + P4.w * r3.y;
            x2 += P4.x * r0.z + P4.y * r1.z + P4.z * r2.z + P4.w * r3.z;
            x3 += P4.x * r0.w + P4.y * r1.w + P4.z * r2.w + P4.w * r3.w;
            y0 += Q4.x * r0.x + Q4.y * r1.x + Q4.z * r2.x + Q4.w * r3.x;
            y1 += Q4.x * r0.y + Q4.y * r1.y + Q4.z * r2.y + Q4.w * r3.y;
            y2 += Q4.x * r0.z + Q4.y * r1.z + Q4.z * r2.z + Q4.w * r3.z;
            y3 += Q4.x * r0.w + Q4.y * r1.w + Q4.z * r2.w + Q4.w * r3.w;
        } else {
            int e0 = v0 - VOCAB;
            const float4 W4 = *reinterpret_cast<const float4*>(&ws[OFF_EXPW + e0]);
            const float4 r0 = *reinterpret_cast<const float4*>(&te1[(size_t)(e0 + 0) * D + j0]);
            const float4 r1 = *reinterpret_cast<const float4*>(&te1[(size_t)(e0 + 1) * D + j0]);
            const float4 r2 = *reinterpret_cast<const float4*>(&te1[(size_t)(e0 + 2) * D + j0]);
            const float4 r3 = *reinterpret_cast<const float4*>(&te1[(size_t)(e0 + 3) * D + j0]);
            t0 += W4.x * r0.x + W4.y * r1.x + W4.z * r2.x + W4.w * r3.x;
            t1 += W4.x * r0.y + W4.y * r1.y + W4.z * r2.y + W4.w * r3.y;
            t2 += W4.x * r0.z + W4.y * r1.z + W4.z * r2.z + W4.w * r3.z;
            t3 += W4.x * r0.w + W4.y * r1.w + W4.z * r2.w + W4.w * r3.w;
        }
    }
    atomicAdd(&sAcc[j0 + 0], x0); atomicAdd(&sAcc[j0 + 1], x1);
    atomicAdd(&sAcc[j0 + 2], x2); atomicAdd(&sAcc[j0 + 3], x3);
    atomicAdd(&sAcc[256 + j0 + 0], y0); atomicAdd(&sAcc[256 + j0 + 1], y1);
    atomicAdd(&sAcc[256 + j0 + 2], y2); atomicAdd(&sAcc[256 + j0 + 3], y3);
    atomicAdd(&sAcc[512 + j0 + 0], t0); atomicAdd(&sAcc[512 + j0 + 1], t1);
    atomicAdd(&sAcc[512 + j0 + 2], t2); atomicAdd(&sAcc[512 + j0 + 3], t3);
    __syncthreads();
    float* base = &ws[OFF_XYP + (size_t)blockIdx.x * K6_STRIDE];
    for (int i = tid; i < K6_STRIDE; i += 256) base[i] = sAcc[i];
}

// K6b: reduce XYP[K6_BLOCKS][768] over blocks -> X / Y / WTE1 (grid 192, 4 slots each).
__global__ void k6b_reduce(float* __restrict__ ws) {
    __shared__ float sR[256 * 4];
    int tid = threadIdx.x;
    int s0 = blockIdx.x * 4;
    float a0 = 0.f, a1 = 0.f, a2 = 0.f, a3 = 0.f;
#pragma unroll
    for (int r = 0; r < K6_BLOCKS / 256; ++r) {
        int b = tid + r * 256;
        const float4 v = *reinterpret_cast<const float4*>(&ws[OFF_XYP + (size_t)b * K6_STRIDE + s0]);
        a0 += v.x; a1 += v.y; a2 += v.z; a3 += v.w;
    }
    sR[tid * 4 + 0] = a0; sR[tid * 4 + 1] = a1;
    sR[tid * 4 + 2] = a2; sR[tid * 4 + 3] = a3;
    __syncthreads();
#pragma unroll
    for (int off = 128; off > 0; off >>= 1) {
        if (tid < off) {
#pragma unroll
            for (int c = 0; c < 4; ++c) sR[tid * 4 + c] += sR[(tid + off) * 4 + c];
        }
        __syncthreads();
    }
    if (tid < 4) {
        int s = s0 + tid;
        float v = sR[tid];
        if (s < 256)      ws[OFF_X + s] = v;
        else if (s < 512) ws[OFF_Y + s - 256] = v;
        else              ws[OFF_WTE1 + s - 512] = v;
    }
}

// K8: sumw from SWP; features = (u*X + s*Y + WTE1)/sumw + qemb; expL + per-block partial LP.
__global__ void k8_logits(const float* __restrict__ Wm, const float* __restrict__ bv,
                          float* __restrict__ ws) {
    __shared__ float sF[D];
    __shared__ float sRed[256];
    __shared__ float sPart[4];
    int tid = threadIdx.x;
    // reduce SWP[512] -> sumw (redundantly per block; 2 KB L2-hot)
    sRed[tid] = ws[OFF_SWP + tid] + ws[OFF_SWP + 256 + tid];
    __syncthreads();
#pragma unroll
    for (int off = 128; off > 0; off >>= 1) {
        if (tid < off) sRed[tid] += sRed[tid + off];
        __syncthreads();
    }
    float invw = 1.f / sRed[0];
    sF[tid] = (u_of(tid) * ws[OFF_X + tid] + s_of(tid) * ws[OFF_Y + tid] +
               ws[OFF_WTE1 + tid]) * invw + ws[OFF_QEMB + tid];
    __syncthreads();
    int wv = tid >> 6, lane = tid & 63;
    int gw = blockIdx.x * 4 + wv;
    int stride = gridDim.x * 4;
    int j0 = lane * 4;
    const float4 f = *reinterpret_cast<const float4*>(&sF[j0]);
    float lsum = 0.f;
    for (int v = gw; v < VOCAB; v += stride) {
        const float4 w4 = *reinterpret_cast<const float4*>(&Wm[(size_t)v * D + j0]);
        float p = w4.x * f.x + w4.y * f.y + w4.z * f.z + w4.w * f.w;
        float logit = wave_reduce(p) + bv[v];
        float ex = expf(logit);
        if (lane == 0) ws[OFF_EXPL + v] = ex;
        lsum += ex;
    }
    if (lane == 0) sPart[wv] = lsum;
    __syncthreads();
    if (tid == 0) ws[OFF_LP + blockIdx.x] = sPart[0] + sPart[1] + sPart[2] + sPart[3];
}

// K10: sumL from LP[1024] (per block, L2-hot); out = expL / sumL.
__global__ void k10_norm(float* __restrict__ out, const float* __restrict__ ws) {
    __shared__ float sRed[256];
    int tid = threadIdx.x;
    float l = 0.f;
#pragma unroll
    for (int r = 0; r < 4; ++r) l += ws[OFF_LP + tid + r * 256];
    sRed[tid] = l;
    __syncthreads();
#pragma unroll
    for (int off = 128; off > 0; off >>= 1) {
        if (tid < off) sRed[tid] += sRed[tid + off];
        __syncthreads();
    }
    float invL = 1.f / sRed[0];
    int i = blockIdx.x * 256 + tid;
    if (i < VOCAB) out[i] = ws[OFF_EXPL + i] * invL;
}

extern "C" void kernel_launch(void* const* d_in, const int* in_sizes, int n_in,
                              void* d_out, int out_size, void* d_ws, size_t ws_size,
                              hipStream_t stream) {
    const int*   evidence = (const int*)d_in[0];
    const int*   question = (const int*)d_in[1];
    const float* q_table  = (const float*)d_in[2];
    const float* e_table  = (const float*)d_in[3];
    const float* te1      = (const float*)d_in[4];
    const float* te2      = (const float*)d_in[5];
    const float* Wm       = (const float*)d_in[6];
    const float* bv       = (const float*)d_in[7];
    float* out = (float*)d_out;
    float* ws  = (float*)d_ws;

    const bool big = ws_size >= (size_t)WS_FLOATS * sizeof(float);

    k1_qemb<<<1, 256, 0, stream>>>(question, q_table, ws);
    k2_ab<<<VOCAB / 4, 256, 0, stream>>>(q_table, ws);
    k3_scores<<<512, 256, 0, stream>>>(evidence, te2, ws);
    if (big) {
        k5_scatter2<<<NCHUNK * NSLICE, 256, 0, stream>>>(evidence, ws);
        k5b_reduce<<<(VOCAB + 255) / 256, 256, 0, stream>>>(ws);
    } else {
        k5_scatter<<<512, 256, 0, stream>>>(evidence, ws);  // P/Q zeroed by k2
    }
    k6_xyt<<<K6_BLOCKS, 256, 0, stream>>>(e_table, te1, ws);
    k6b_reduce<<<K6_STRIDE / 4, 256, 0, stream>>>(ws);
    k8_logits<<<1024, 256, 0, stream>>>(Wm, bv, ws);
    k10_norm<<<(VOCAB + 255) / 256, 256, 0, stream>>>(out, ws);
}

// Round 9
// 249.933 us; speedup vs baseline: 1.2505x; 1.0266x over previous
//
#include <hip/hip_runtime.h>

// Problem constants
#define D      256
#define L_W    20
#define E_CNT  20000
#define VOCAB  50000
#define TOTROW (VOCAB + E_CNT)   // k6 streams e_table rows then te1 rows

// Scatter privatization geometry
#define CHUNK   1024
#define NCHUNK  49                   // 49*1024 = 50176 >= VOCAB
#define NSLICE  4
#define RPS     (E_CNT / NSLICE)     // 5000 rows per slice
#define PSTRIDE (NCHUNK * CHUNK)     // 50176

// k6 geometry
#define K6_BLOCKS 512
#define K6_STRIDE 768                // X(256) | Y(256) | T(256) per block

// Workspace layout (float offsets) — all atomic-free partials
#define OFF_QEMB  0                              // [256]
#define OFF_X     256                            // [256]
#define OFF_Y     512                            // [256]
#define OFF_WTE1  768                            // [256]
#define OFF_SWP   1024                           // [512]  k3 per-block exp-sum partials
#define OFF_LP    1536                           // [1024] k8 per-block expL-sum partials
#define OFF_A     2560                           // [VOCAB]
#define OFF_B     (OFF_A + VOCAB)                // [VOCAB]
#define OFF_P     (OFF_B + VOCAB)                // [VOCAB]
#define OFF_Q     (OFF_P + VOCAB)                // [VOCAB]
#define OFF_EXPW  (OFF_Q + VOCAB)                // [E_CNT]
#define OFF_EXPL  (OFF_EXPW + E_CNT)             // [VOCAB]
#define OFF_PPART (OFF_EXPL + VOCAB)             // [NSLICE][PSTRIDE]
#define OFF_QPART (OFF_PPART + NSLICE * PSTRIDE) // [NSLICE][PSTRIDE]
#define OFF_XYP   (OFF_QPART + NSLICE * PSTRIDE) // [K6_BLOCKS][768]
#define WS_FLOATS (OFF_XYP + K6_BLOCKS * K6_STRIDE)  // 1,067,184 floats ~= 4.27 MB

__device__ __forceinline__ float wave_reduce(float v) {
#pragma unroll
    for (int o = 32; o > 0; o >>= 1) v += __shfl_xor(v, o, 64);
    return v;
}
// all-reduce within 16-lane group (butterfly; all lanes end with the sum)
__device__ __forceinline__ float group16_reduce(float v) {
#pragma unroll
    for (int o = 1; o < 16; o <<= 1) v += __shfl_xor(v, o, 64);
    return v;
}

// u_j = 1 - 2j/D, s_j = j/D;  pe[l][j] = a_l*u_j + s_j with a_l = 1 - l/L
__device__ __forceinline__ float u_of(int j) { return 1.f - (float)j * (1.f / 128.f); }
__device__ __forceinline__ float s_of(int j) { return (float)j * (1.f / 256.f); }

// K2 (k1 fused in): every block builds q_emb in LDS (20 L2-hot rows); block 0 publishes.
// Then grid-stride A/B: 16-lane group per vocab row, 4 rows/wave/iter, 4 float4 loads in flight.
__global__ void k2_ab(const int* __restrict__ question,
                      const float* __restrict__ q_table,
                      float* __restrict__ ws) {
    __shared__ int sQ[L_W];
    __shared__ float sQE[D];
    int tid = threadIdx.x;
    if (tid < L_W) sQ[tid] = question[tid];
    __syncthreads();
    {
        float u = u_of(tid), s = s_of(tid);
        float acc = 0.f;
#pragma unroll
        for (int i = 0; i < L_W; ++i) {
            float a = 1.f - (float)i * (1.f / (float)L_W);
            acc += q_table[(size_t)sQ[i] * D + tid] * (a * u + s);
        }
        sQE[tid] = acc;
        if (blockIdx.x == 0) ws[OFF_QEMB + tid] = acc;
    }
    __syncthreads();
    int wv = tid >> 6, lane = tid & 63, g = lane >> 4, li = lane & 15;
    int gw = blockIdx.x * 4 + wv, nw = gridDim.x * 4;
    for (int v0 = gw * 4; v0 < VOCAB; v0 += nw * 4) {
        int row = v0 + g;
        const float* rp = q_table + (size_t)row * D;
        float accA = 0.f, accB = 0.f;
#pragma unroll
        for (int c = 0; c < 4; ++c) {
            int j = c * 64 + li * 4;
            const float4 q  = *reinterpret_cast<const float4*>(rp + j);
            const float4 qe = *reinterpret_cast<const float4*>(&sQE[j]);
            accA += q.x * (u_of(j + 0) * qe.x) + q.y * (u_of(j + 1) * qe.y) +
                    q.z * (u_of(j + 2) * qe.z) + q.w * (u_of(j + 3) * qe.w);
            accB += q.x * (s_of(j + 0) * qe.x) + q.y * (s_of(j + 1) * qe.y) +
                    q.z * (s_of(j + 2) * qe.z) + q.w * (s_of(j + 3) * qe.w);
        }
        accA = group16_reduce(accA);
        accB = group16_reduce(accB);
        if (li == 0) {
            ws[OFF_A + row] = accA;
            ws[OFF_B + row] = accB;
            ws[OFF_P + row] = 0.f;   // for small-ws fallback path
            ws[OFF_Q + row] = 0.f;
        }
    }
}

// K3: 16-lane group per evidence row, 4 rows/wave/iter; per-block partial -> SWP (no atomics).
__global__ void k3_scores(const int* __restrict__ evidence,
                          const float* __restrict__ te2,
                          float* __restrict__ ws) {
    __shared__ float sQE[D];
    __shared__ float sPart[4];
    int tid = threadIdx.x;
    sQE[tid] = ws[OFF_QEMB + tid];
    __syncthreads();
    int wv = tid >> 6, lane = tid & 63, g = lane >> 4, li = lane & 15;
    int gw = blockIdx.x * 4 + wv, nw = gridDim.x * 4;
    float wsum = 0.f;
    for (int e0 = gw * 4; e0 < E_CNT; e0 += nw * 4) {
        int e = e0 + g;
        const float* tp = te2 + (size_t)e * D;
        float p = 0.f;
#pragma unroll
        for (int c = 0; c < 4; ++c) {
            int j = c * 64 + li * 4;
            const float4 t  = *reinterpret_cast<const float4*>(tp + j);
            const float4 qe = *reinterpret_cast<const float4*>(&sQE[j]);
            p += t.x * qe.x + t.y * qe.y + t.z * qe.z + t.w * qe.w;
        }
        {
            int idx = evidence[e * L_W + li];
            float a = 1.f - (float)li * (1.f / (float)L_W);
            p += a * ws[OFF_A + idx] + ws[OFF_B + idx];
            if (li < L_W - 16) {
                int w2 = li + 16;
                int idx2 = evidence[e * L_W + w2];
                float a2 = 1.f - (float)w2 * (1.f / (float)L_W);
                p += a2 * ws[OFF_A + idx2] + ws[OFF_B + idx2];
            }
        }
        p = group16_reduce(p);
        float ex = expf(p);
        if (li == 0) { ws[OFF_EXPW + e] = ex; wsum += ex; }
    }
    wsum = wave_reduce(wsum);
    if (lane == 0) sPart[wv] = wsum;
    __syncthreads();
    if (tid == 0) ws[OFF_SWP + blockIdx.x] = sPart[0] + sPart[1] + sPart[2] + sPart[3];
}

// K5v2: atomic-free P/Q scatter with UNNORMALIZED weights ex_e (LDS atomics only).
__global__ void k5_scatter2(const int* __restrict__ evidence, float* __restrict__ ws) {
    __shared__ float sP[CHUNK], sQ[CHUNK];
    int tid = threadIdx.x;
    int chunk = blockIdx.x % NCHUNK;
    int slice = blockIdx.x / NCHUNK;
    for (int i = tid; i < CHUNK; i += 256) { sP[i] = 0.f; sQ[i] = 0.f; }
    __syncthreads();
    int lo = chunk * CHUNK;
    int r0 = slice * RPS;
    for (int r = tid; r < RPS; r += 256) {
        int e = r0 + r;
        float w = ws[OFF_EXPW + e];
        const int4* rp = reinterpret_cast<const int4*>(evidence + (size_t)e * L_W);
        int4 v0 = rp[0], v1 = rp[1], v2 = rp[2], v3 = rp[3], v4 = rp[4];
        int idxs[L_W] = {v0.x, v0.y, v0.z, v0.w, v1.x, v1.y, v1.z, v1.w,
                         v2.x, v2.y, v2.z, v2.w, v3.x, v3.y, v3.z, v3.w,
                         v4.x, v4.y, v4.z, v4.w};
#pragma unroll
        for (int l = 0; l < L_W; ++l) {
            int d = idxs[l] - lo;
            if ((unsigned)d < (unsigned)CHUNK) {
                float a = 1.f - (float)l * (1.f / (float)L_W);
                atomicAdd(&sP[d], w * a);
                atomicAdd(&sQ[d], w);
            }
        }
    }
    __syncthreads();
    float* pp = &ws[OFF_PPART + (size_t)slice * PSTRIDE + (size_t)chunk * CHUNK];
    float* qp = &ws[OFF_QPART + (size_t)slice * PSTRIDE + (size_t)chunk * CHUNK];
    for (int i = tid; i < CHUNK; i += 256) { pp[i] = sP[i]; qp[i] = sQ[i]; }
}

// K5 fallback (small ws): atomic P/Q scatter with raw ex (P/Q zeroed by k2).
__global__ void k5_scatter(const int* __restrict__ evidence, float* __restrict__ ws) {
    int tid = threadIdx.x;
    int wv = tid >> 6, lane = tid & 63;
    int gw = blockIdx.x * 4 + wv;
    int stride = gridDim.x * 4;
    for (int e = gw; e < E_CNT; e += stride) {
        float w = ws[OFF_EXPW + e];
        if (lane < L_W) {
            int idx = evidence[e * L_W + lane];
            float a = 1.f - (float)lane * (1.f / (float)L_W);
            atomicAdd(&ws[OFF_P + idx], w * a);
            atomicAdd(&ws[OFF_Q + idx], w);
        }
    }
}

// K6: fused stream of e_table (P/Q-weighted, slice partials summed inline) + te1 (EXPW-weighted).
// Full-wave row loads, 4 rows/iter; LDS combine; non-atomic per-block partial [768].
__global__ void k6_xyt(const float* __restrict__ e_table,
                       const float* __restrict__ te1,
                       const float* __restrict__ Pp,
                       const float* __restrict__ Qp,
                       int nslice,
                       float* __restrict__ ws) {
    __shared__ float sAcc[K6_STRIDE];
    int tid = threadIdx.x;
    for (int i = tid; i < K6_STRIDE; i += 256) sAcc[i] = 0.f;
    __syncthreads();
    int wv = tid >> 6, lane = tid & 63;
    int gw = blockIdx.x * 4 + wv;
    int nw = gridDim.x * 4;
    int j0 = lane * 4;
    float x0 = 0.f, x1 = 0.f, x2 = 0.f, x3 = 0.f;
    float y0 = 0.f, y1 = 0.f, y2 = 0.f, y3 = 0.f;
    float t0 = 0.f, t1 = 0.f, t2 = 0.f, t3 = 0.f;
    for (int v0 = gw * 4; v0 < TOTROW; v0 += nw * 4) {
        if (v0 < VOCAB) {
            float4 P4 = make_float4(0.f, 0.f, 0.f, 0.f);
            float4 Q4 = make_float4(0.f, 0.f, 0.f, 0.f);
            for (int s = 0; s < nslice; ++s) {
                const float4 ps = *reinterpret_cast<const float4*>(Pp + (size_t)s * PSTRIDE + v0);
                const float4 qs = *reinterpret_cast<const float4*>(Qp + (size_t)s * PSTRIDE + v0);
                P4.x += ps.x; P4.y += ps.y; P4.z += ps.z; P4.w += ps.w;
                Q4.x += qs.x; Q4.y += qs.y; Q4.z += qs.z; Q4.w += qs.w;
            }
            const float4 r0 = *reinterpret_cast<const float4*>(&e_table[(size_t)(v0 + 0) * D + j0]);
            const float4 r1 = *reinterpret_cast<const float4*>(&e_table[(size_t)(v0 + 1) * D + j0]);
            const float4 r2 = *reinterpret_cast<const float4*>(&e_table[(size_t)(v0 + 2) * D + j0]);
            const float4 r3 = *reinterpret_cast<const float4*>(&e_table[(size_t)(v0 + 3) * D + j0]);
            x0 += P4.x * r0.x + P4.y * r1.x + P4.z * r2.x + P4.w * r3.x;
            x1 += P4.x * r0.y + P4.y * r1.y + P4.z * r2.y + P4.w * r3.y;
            x2 += P4.x * r0.z + P4.y * r1.z + P4.z * r2.z + P4.w * r3.z;
            x3 += P4.x * r0.w + P4.y * r1.w + P4.z * r2.w + P4.w * r3.w;
            y0 += Q4.x * r0.x + Q4.y * r1.x + Q4.z * r2.x + Q4.w * r3.x;
            y1 += Q4.x * r0.y + Q4.y * r1.y + Q4.z * r2.y + Q4.w * r3.y;
            y2 += Q4.x * r0.z + Q4.y * r1.z + Q4.z * r2.z + Q4.w * r3.z;
            y3 += Q4.x * r0.w + Q4.y * r1.w + Q4.z * r2.w + Q4.w * r3.w;
        } else {
            int e0 = v0 - VOCAB;
            const float4 W4 = *reinterpret_cast<const float4*>(&ws[OFF_EXPW + e0]);
            const float4 r0 = *reinterpret_cast<const float4*>(&te1[(size_t)(e0 + 0) * D + j0]);
            const float4 r1 = *reinterpret_cast<const float4*>(&te1[(size_t)(e0 + 1) * D + j0]);
            const float4 r2 = *reinterpret_cast<const float4*>(&te1[(size_t)(e0 + 2) * D + j0]);
            const float4 r3 = *reinterpret_cast<const float4*>(&te1[(size_t)(e0 + 3) * D + j0]);
            t0 += W4.x * r0.x + W4.y * r1.x + W4.z * r2.x + W4.w * r3.x;
            t1 += W4.x * r0.y + W4.y * r1.y + W4.z * r2.y + W4.w * r3.y;
            t2 += W4.x * r0.z + W4.y * r1.z + W4.z * r2.z + W4.w * r3.z;
            t3 += W4.x * r0.w + W4.y * r1.w + W4.z * r2.w + W4.w * r3.w;
        }
    }
    atomicAdd(&sAcc[j0 + 0], x0); atomicAdd(&sAcc[j0 + 1], x1);
    atomicAdd(&sAcc[j0 + 2], x2); atomicAdd(&sAcc[j0 + 3], x3);
    atomicAdd(&sAcc[256 + j0 + 0], y0); atomicAdd(&sAcc[256 + j0 + 1], y1);
    atomicAdd(&sAcc[256 + j0 + 2], y2); atomicAdd(&sAcc[256 + j0 + 3], y3);
    atomicAdd(&sAcc[512 + j0 + 0], t0); atomicAdd(&sAcc[512 + j0 + 1], t1);
    atomicAdd(&sAcc[512 + j0 + 2], t2); atomicAdd(&sAcc[512 + j0 + 3], t3);
    __syncthreads();
    float* base = &ws[OFF_XYP + (size_t)blockIdx.x * K6_STRIDE];
    for (int i = tid; i < K6_STRIDE; i += 256) base[i] = sAcc[i];
}

// K6b: reduce XYP[K6_BLOCKS][768] over blocks -> X / Y / WTE1 (grid 192, 4 slots each).
__global__ void k6b_reduce(float* __restrict__ ws) {
    __shared__ float sR[256 * 4];
    int tid = threadIdx.x;
    int s0 = blockIdx.x * 4;
    float a0 = 0.f, a1 = 0.f, a2 = 0.f, a3 = 0.f;
#pragma unroll
    for (int r = 0; r < K6_BLOCKS / 256; ++r) {
        int b = tid + r * 256;
        const float4 v = *reinterpret_cast<const float4*>(&ws[OFF_XYP + (size_t)b * K6_STRIDE + s0]);
        a0 += v.x; a1 += v.y; a2 += v.z; a3 += v.w;
    }
    sR[tid * 4 + 0] = a0; sR[tid * 4 + 1] = a1;
    sR[tid * 4 + 2] = a2; sR[tid * 4 + 3] = a3;
    __syncthreads();
#pragma unroll
    for (int off = 128; off > 0; off >>= 1) {
        if (tid < off) {
#pragma unroll
            for (int c = 0; c < 4; ++c) sR[tid * 4 + c] += sR[(tid + off) * 4 + c];
        }
        __syncthreads();
    }
    if (tid < 4) {
        int s = s0 + tid;
        float v = sR[tid];
        if (s < 256)      ws[OFF_X + s] = v;
        else if (s < 512) ws[OFF_Y + s - 256] = v;
        else              ws[OFF_WTE1 + s - 512] = v;
    }
}

// K8: sumw from SWP; features = (u*X + s*Y + WTE1)/sumw + qemb; 16-lane groups, 4 rows/wave/iter.
__global__ void k8_logits(const float* __restrict__ Wm, const float* __restrict__ bv,
                          float* __restrict__ ws) {
    __shared__ float sF[D];
    __shared__ float sRed[256];
    __shared__ float sPart[4];
    int tid = threadIdx.x;
    sRed[tid] = ws[OFF_SWP + tid] + ws[OFF_SWP + 256 + tid];
    __syncthreads();
#pragma unroll
    for (int off = 128; off > 0; off >>= 1) {
        if (tid < off) sRed[tid] += sRed[tid + off];
        __syncthreads();
    }
    float invw = 1.f / sRed[0];
    sF[tid] = (u_of(tid) * ws[OFF_X + tid] + s_of(tid) * ws[OFF_Y + tid] +
               ws[OFF_WTE1 + tid]) * invw + ws[OFF_QEMB + tid];
    __syncthreads();
    int wv = tid >> 6, lane = tid & 63, g = lane >> 4, li = lane & 15;
    int gw = blockIdx.x * 4 + wv, nw = gridDim.x * 4;
    float lsum = 0.f;
    for (int v0 = gw * 4; v0 < VOCAB; v0 += nw * 4) {
        int row = v0 + g;
        const float* wp = Wm + (size_t)row * D;
        float p = 0.f;
#pragma unroll
        for (int c = 0; c < 4; ++c) {
            int j = c * 64 + li * 4;
            const float4 w4 = *reinterpret_cast<const float4*>(wp + j);
            const float4 f4 = *reinterpret_cast<const float4*>(&sF[j]);
            p += w4.x * f4.x + w4.y * f4.y + w4.z * f4.z + w4.w * f4.w;
        }
        p = group16_reduce(p);
        float ex = expf(p + bv[row]);
        if (li == 0) { ws[OFF_EXPL + row] = ex; lsum += ex; }
    }
    lsum = wave_reduce(lsum);
    if (lane == 0) sPart[wv] = lsum;
    __syncthreads();
    if (tid == 0) ws[OFF_LP + blockIdx.x] = sPart[0] + sPart[1] + sPart[2] + sPart[3];
}

// K10: sumL from LP[1024] (per block, L2-hot); out = expL / sumL.
__global__ void k10_norm(float* __restrict__ out, const float* __restrict__ ws) {
    __shared__ float sRed[256];
    int tid = threadIdx.x;
    float l = 0.f;
#pragma unroll
    for (int r = 0; r < 4; ++r) l += ws[OFF_LP + tid + r * 256];
    sRed[tid] = l;
    __syncthreads();
#pragma unroll
    for (int off = 128; off > 0; off >>= 1) {
        if (tid < off) sRed[tid] += sRed[tid + off];
        __syncthreads();
    }
    float invL = 1.f / sRed[0];
    int i = blockIdx.x * 256 + tid;
    if (i < VOCAB) out[i] = ws[OFF_EXPL + i] * invL;
}

extern "C" void kernel_launch(void* const* d_in, const int* in_sizes, int n_in,
                              void* d_out, int out_size, void* d_ws, size_t ws_size,
                              hipStream_t stream) {
    const int*   evidence = (const int*)d_in[0];
    const int*   question = (const int*)d_in[1];
    const float* q_table  = (const float*)d_in[2];
    const float* e_table  = (const float*)d_in[3];
    const float* te1      = (const float*)d_in[4];
    const float* te2      = (const float*)d_in[5];
    const float* Wm       = (const float*)d_in[6];
    const float* bv       = (const float*)d_in[7];
    float* out = (float*)d_out;
    float* ws  = (float*)d_ws;

    const bool big = ws_size >= (size_t)WS_FLOATS * sizeof(float);

    k2_ab<<<1024, 256, 0, stream>>>(question, q_table, ws);
    k3_scores<<<512, 256, 0, stream>>>(evidence, te2, ws);
    if (big) {
        k5_scatter2<<<NCHUNK * NSLICE, 256, 0, stream>>>(evidence, ws);
        k6_xyt<<<K6_BLOCKS, 256, 0, stream>>>(e_table, te1,
                                              &ws[OFF_PPART], &ws[OFF_QPART], NSLICE, ws);
    } else {
        k5_scatter<<<512, 256, 0, stream>>>(evidence, ws);  // P/Q zeroed by k2
        k6_xyt<<<K6_BLOCKS, 256, 0, stream>>>(e_table, te1,
                                              &ws[OFF_P], &ws[OFF_Q], 1, ws);
    }
    k6b_reduce<<<K6_STRIDE / 4, 256, 0, stream>>>(ws);
    k8_logits<<<1024, 256, 0, stream>>>(Wm, bv, ws);
    k10_norm<<<(VOCAB + 255) / 256, 256, 0, stream>>>(out, ws);
}